// Round 9
// baseline (904.422 us; speedup 1.0000x reference)
//
#include <hip/hip_runtime.h>

#define H 512
#define MTILE 32
#define NBLK 16384
#define STEPC (2.4f / 63.0f)

typedef _Float16 half8 __attribute__((ext_vector_type(8)));
typedef _Float16 half4_t __attribute__((ext_vector_type(4)));
typedef float floatx16 __attribute__((ext_vector_type(16)));
typedef float floatx4 __attribute__((ext_vector_type(4)));
typedef float floatx2 __attribute__((ext_vector_type(2)));

// fast silu: native exp + fast div. rel-err ~1e-7, negligible vs fp16 rounding.
__device__ inline float silu_f(float x) {
    return __fdividef(x, 1.0f + __expf(-x));
}

// ---- fused prep: blocks 0..1023 -> W image; blocks 1024..1025 -> latw ----
// W image layout: [l][wv][hi][ks][nt][lm][e]  (halves)
//   idx = (l*8+wv)*32768 + hi*16384 + ks*512 + nt*256 + lm*8 + e
// (unchanged from R6-R8: wave wv owns n-columns wv*64 .. wv*64+63)
__global__ void prep_fused(const float* __restrict__ lat, const float* __restrict__ W0,
                           const float* __restrict__ b0,
                           const float* __restrict__ W1, const float* __restrict__ W2,
                           float* __restrict__ latw, _Float16* __restrict__ ws) {
    __shared__ float sl[H];
    if (blockIdx.x < 1024) {
        const int id = blockIdx.x * 512 + threadIdx.x;   // 0 .. 524287
        const int l = id >> 18;
        const int rem = id & 0x3FFFF;                    // k*512 + n
        const int k = rem >> 9, n = rem & 511;
        const float w = (l == 0 ? W1 : W2)[rem];
        const int ks = k >> 4, hi = (k >> 3) & 1, e = k & 7;
        const int wv = n >> 6, nt = (n >> 5) & 1, lm = n & 31;
        ws[(size_t)(l * 8 + wv) * 32768 + hi * 16384 + ks * 512 + nt * 256 + lm * 8 + e]
            = (_Float16)w;
    } else {
        const int b = blockIdx.x - 1024;
        const int j = threadIdx.x;
        sl[j] = lat[b * H + j];
        __syncthreads();
        float acc = b0[j];
#pragma unroll 8
        for (int d = 0; d < H; ++d) acc += sl[d] * W0[d * H + j];
        latw[b * H + j] = acc;
    }
}

// ---- main fused kernel ----
// R9: OCCUPANCY RESHAPE. 8 rounds proved every per-wave lever is
// time-invariant (conflicts, VALU, issue count, forced prefetch w/ counted
// vmcnt, SALU addressing): dur pinned at 744-775, MfmaUtil 35, occupancy
// 44%. The one never-changed parameter: 128 unified regs/thread (64 acc
// AGPR + 64 VGPR) = 4 waves/SIMD in every variant. R9 halves the wave
// accumulator: MTILE 32, wave tile 32x64, acc = 2 x 32x32 = 32 AGPR,
// ~50 VGPR, launch_bounds(512,6) -> 3 blocks/CU, 24 waves/CU (75%).
// LDS 35.3 KB/block (h 32 KB + lw 4 KB + partials 1 KB) -> 106 KB for 3.
// Per ks: 2 global b128 (W, nt=0/1) + 1 ds b128 (A) + 2 MFMA, 2-deep
// compiler-scheduled double-buffer. Layouts inherited from R8 (verified).
// Grid 16384: z axis split in two 32-row half-tiles per (b,x,y);
// phase-A (lw) duplicated per half -- accepted ~+20-40us (R5 lesson).
__global__ __launch_bounds__(512, 6) void mesh_main(
    const float* __restrict__ W0, const float* __restrict__ b1,
    const float* __restrict__ b2, const float* __restrict__ W3,
    const float* __restrict__ b3, const float* __restrict__ latw,
    const _Float16* __restrict__ wsB, float* __restrict__ out) {

    __shared__ _Float16 hbuf2[2048 * 8];          // 32 KB, fragment-major h (32 rows)
    __shared__ float lwbuf[2 * H];                // 4 KB: (lw, w2c) pairs
    __shared__ float partials[8][MTILE];          // 1 KB  -> 37 KB total

    const int tid = threadIdx.x;
    const int wave = tid >> 6, lane = tid & 63;
    const int lm = lane & 31, hi = lane >> 5;
    const int uwave = __builtin_amdgcn_readfirstlane(wave);  // force SGPR
    const int bi = blockIdx.x;
    const int b = bi >> 13;                        // 2 latents
    const int xy = (bi >> 1) & 4095;
    const int zh = bi & 1;                         // z half-tile
    const float c0 = -1.2f + (float)(xy >> 6) * STEPC;
    const float c1 = -1.2f + (float)(xy & 63) * STEPC;
    const float z0 = -1.2f + (float)(zh << 5) * STEPC;

    // ---- layer 0, phase A: lw[j] = latw + c0*W0x + c1*W0y; w2c[j] = W0z ----
    {
        const int j = tid;
        const float lwv = latw[b * H + j]
                        + c0 * W0[(H + 0) * H + j]
                        + c1 * W0[(H + 1) * H + j];
        floatx2 v;
        v[0] = lwv;
        v[1] = W0[(H + 2) * H + j];
        *(floatx2*)&lwbuf[2 * j] = v;
    }
    __syncthreads();

    // ---- layer 0, phase B: rows m = lm (32); regions g = (wave*2+hi)*4+s ----
    {
        const float c2v = z0 + (float)lm * STEPC;
#pragma unroll
        for (int s = 0; s < 4; ++s) {
            const int g = (wave * 2 + hi) * 4 + s;          // 0..63
            const floatx4* lp = (const floatx4*)&lwbuf[g * 16];  // broadcast reads
            half8 hv;
#pragma unroll
            for (int i = 0; i < 4; ++i) {
                const floatx4 pv = lp[i];          // (lw, w2c, lw, w2c)
                hv[2 * i + 0] = (_Float16)silu_f(pv[0] + c2v * pv[1]);
                hv[2 * i + 1] = (_Float16)silu_f(pv[2] + c2v * pv[3]);
            }
            *(half8*)&hbuf2[(g * 32 + lm) * 8] = hv;
        }
    }

    // per-lane bases
    const _Float16* hb = hbuf2 + hi * 256 + lm * 8;      // A: LDS base, imm offsets
    const _Float16* wsl0 = wsB + (size_t)uwave * 32768 + hi * 16384 + lm * 8;

    floatx16 acc[2];                               // nt = 0,1: 32 AGPR

    auto zero_acc = [&]() {
#pragma unroll
        for (int nt = 0; nt < 2; ++nt)
#pragma unroll
            for (int r = 0; r < 16; ++r) acc[nt][r] = 0.f;
    };

    auto loadW = [&](const _Float16* base, int ks, half8 (&wf)[2]) {
        const _Float16* p = base + ks * 512;
        wf[0] = *(const half8*)(p);            // nt=0
        wf[1] = *(const half8*)(p + 256);      // nt=1
    };

    auto loadA = [&](int ks) -> half8 {
        return *(const half8*)(hb + ks * 512); // pure offset-imm ds_read
    };

    auto compute = [&](half8 (&wf)[2], half8 a) {
#pragma unroll
        for (int nt = 0; nt < 2; ++nt)
            acc[nt] = __builtin_amdgcn_mfma_f32_32x32x16_f16(wf[nt], a, acc[nt], 0, 0, 0);
    };

    // 2-deep double-buffered K-loop, compiler-scheduled (R8: forcing buys 0)
    auto run_gemm = [&](const _Float16* base) {
        half8 Wb0[2], Wb1[2], a0, a1;
        loadW(base, 0, Wb0); a0 = loadA(0);
        loadW(base, 1, Wb1); a1 = loadA(1);
#pragma unroll 1
        for (int ks = 0; ks < 30; ks += 2) {
            compute(Wb0, a0);
            loadW(base, ks + 2, Wb0); a0 = loadA(ks + 2);
            compute(Wb1, a1);
            loadW(base, ks + 3, Wb1); a1 = loadA(ks + 3);
        }
        compute(Wb0, a0);
        compute(Wb1, a1);
    };

    // ---- GEMM 1 ----
    zero_acc();
    __syncthreads();             // h0 ready
    run_gemm(wsl0);
    __syncthreads();             // all waves done reading h0
    // writeback h1 = silu(acc + b1): lane owns, per (nt,g), 4 consecutive
    // n = wave*64 + nt*32 + g*8 + hi*4 .. +3 at row m = lm.
    // region g2 = wave*8 + nt*4 + g, elem offset hi*4 -> packed b64, conflict-free
    {
        _Float16* wb = hbuf2 + (wave * 8) * 256 + lm * 8 + hi * 4;
#pragma unroll
        for (int nt = 0; nt < 2; ++nt)
#pragma unroll
            for (int g = 0; g < 4; ++g) {
                const floatx4 b1v = *(const floatx4*)&b1[wave * 64 + nt * 32 + g * 8 + hi * 4];
                half4_t hv;
#pragma unroll
                for (int j = 0; j < 4; ++j)
                    hv[j] = (_Float16)silu_f(acc[nt][g * 4 + j] + b1v[j]);
                *(half4_t*)(wb + (nt * 4 + g) * 256) = hv;
            }
    }

    // ---- GEMM 2 ----
    zero_acc();
    __syncthreads();             // h1 ready
    run_gemm(wsl0 + 8 * 32768);  // l=1 image half
    // ---- final layer: out = silu(acc + b2) @ W3 + b3, fp32 VALU ----
    {
        float sum = 0.f;
#pragma unroll
        for (int nt = 0; nt < 2; ++nt)
#pragma unroll
            for (int g = 0; g < 4; ++g) {
                const int n0 = wave * 64 + nt * 32 + g * 8 + hi * 4;
                const floatx4 b2v = *(const floatx4*)&b2[n0];
                const floatx4 w3v = *(const floatx4*)&W3[n0];
#pragma unroll
                for (int j = 0; j < 4; ++j)
                    sum += silu_f(acc[nt][g * 4 + j] + b2v[j]) * w3v[j];
            }
        sum += __shfl_xor(sum, 32);        // combine hi halves (same m = lm)
        if (hi == 0) partials[wave][lm] = sum;
    }
    __syncthreads();
    if (tid < MTILE) {
        float o = b3[0];
#pragma unroll
        for (int w = 0; w < 8; ++w) o += partials[w][tid];
        out[(size_t)(bi >> 1) * 64 + (bi & 1) * 32 + tid] = o;
    }
}

extern "C" void kernel_launch(void* const* d_in, const int* in_sizes, int n_in,
                              void* d_out, int out_size, void* d_ws, size_t ws_size,
                              hipStream_t stream) {
    const float* lat = (const float*)d_in[0];
    const float* W0  = (const float*)d_in[1];
    const float* b0  = (const float*)d_in[2];
    const float* W1  = (const float*)d_in[3];
    const float* b1  = (const float*)d_in[4];
    const float* W2  = (const float*)d_in[5];
    const float* b2  = (const float*)d_in[6];
    const float* W3  = (const float*)d_in[7];
    const float* b3  = (const float*)d_in[8];
    float* out = (float*)d_out;

    float* latw = (float*)d_ws;                               // 4 KB
    _Float16* wsB = (_Float16*)((char*)d_ws + 4096);          // 1 MB

    prep_fused<<<1026, 512, 0, stream>>>(lat, W0, b0, W1, W2, latw, wsB);
    mesh_main<<<NBLK, 512, 0, stream>>>(W0, b1, b2, W3, b3, latw, wsB, out);
}

// Round 10
// 780.280 us; speedup vs baseline: 1.1591x; 1.1591x over previous
//
#include <hip/hip_runtime.h>

#define H 512
#define MTILE 64
#define NBLK 8192
#define STEPC (2.4f / 63.0f)

typedef _Float16 half8 __attribute__((ext_vector_type(8)));
typedef _Float16 half4_t __attribute__((ext_vector_type(4)));
typedef float floatx16 __attribute__((ext_vector_type(16)));
typedef float floatx4 __attribute__((ext_vector_type(4)));
typedef float floatx2 __attribute__((ext_vector_type(2)));

// fast silu: native exp + fast div. rel-err ~1e-7, negligible vs fp16 rounding.
__device__ inline float silu_f(float x) {
    return __fdividef(x, 1.0f + __expf(-x));
}

// ---- fused prep: blocks 0..1023 -> W image; blocks 1024..1025 -> latw ----
// W image layout: [l][wv][hi][ks][nt][lm][e]  (halves)
//   idx = (l*8+wv)*32768 + hi*16384 + ks*512 + nt*256 + lm*8 + e
__global__ void prep_fused(const float* __restrict__ lat, const float* __restrict__ W0,
                           const float* __restrict__ b0,
                           const float* __restrict__ W1, const float* __restrict__ W2,
                           float* __restrict__ latw, _Float16* __restrict__ ws) {
    __shared__ float sl[H];
    if (blockIdx.x < 1024) {
        const int id = blockIdx.x * 512 + threadIdx.x;   // 0 .. 524287
        const int l = id >> 18;
        const int rem = id & 0x3FFFF;                    // k*512 + n
        const int k = rem >> 9, n = rem & 511;
        const float w = (l == 0 ? W1 : W2)[rem];
        const int ks = k >> 4, hi = (k >> 3) & 1, e = k & 7;
        const int wv = n >> 6, nt = (n >> 5) & 1, lm = n & 31;
        ws[(size_t)(l * 8 + wv) * 32768 + hi * 16384 + ks * 512 + nt * 256 + lm * 8 + e]
            = (_Float16)w;
    } else {
        const int b = blockIdx.x - 1024;
        const int j = threadIdx.x;
        sl[j] = lat[b * H + j];
        __syncthreads();
        float acc = b0[j];
#pragma unroll 8
        for (int d = 0; d < H; ++d) acc += sl[d] * W0[d * H + j];
        latw[b * H + j] = acc;
    }
}

// ---- main fused kernel ----
// R10: DRAIN-FREE BARRIERS + CROSS-PHASE PREFETCH (+T5).
// R0-R9 ledger: conflicts -9x, VALU -10pts, MFMA -2x, forced prefetch,
// SALU addressing, 3 concurrency shapes, occupancy 44->65% -- dur pinned
// 744-850, MfmaUtil 33-36. Accounting: MFMA demand 35% (= MfmaUtil: pipe
// never contended), silu-VALU ~21%, ~44% = barrier glue. __syncthreads
// emits s_waitcnt vmcnt(0) -> drains the W queue at EVERY phase edge +
// cold restart (the documented m97 barrier-drain stall).
// Change set vs R8 (otherwise verbatim):
//  (1) all mid-kernel syncs = sched_barrier(0); s_waitcnt lgkmcnt(0);
//      s_barrier; sched_barrier(0). Legal: every cross-wave handoff is
//      via LDS (lgkmcnt); no cross-wave global communication exists.
//  (2) G1's first 3 W-chunk pairs issued BEFORE the h0 barrier (during
//      layer-0); G2's issued after WB's b1 consumption, BEFORE the h1
//      barrier -> queue alive across barriers, K-loops never start cold.
//  (3) T5: s_setprio(1) around the 4-MFMA cluster (2 blocks/CU now have
//      role-split: one in K-loop, one in a VALU phase).
__global__ __launch_bounds__(512, 4) void mesh_main(
    const float* __restrict__ W0, const float* __restrict__ b1,
    const float* __restrict__ b2, const float* __restrict__ W3,
    const float* __restrict__ b3, const float* __restrict__ latw,
    const _Float16* __restrict__ wsB, float* __restrict__ out) {

    __shared__ _Float16 hbuf2[4096 * 8];          // 64 KB, fragment-major h
    __shared__ float lwbuf[2 * H];                // 4 KB
    __shared__ float partials[8][MTILE];          // 2 KB  -> 70 KB total

    const int tid = threadIdx.x;
    const int wave = tid >> 6, lane = tid & 63;
    const int lm = lane & 31, hi = lane >> 5;
    const int uwave = __builtin_amdgcn_readfirstlane(wave);  // force SGPR
    const int bi = blockIdx.x;
    const int b = bi >> 12;
    const int p0 = (bi & 4095) << 6;              // 64 rows per block (fixed x,y)
    const float c0 = -1.2f + (float)(p0 >> 12) * STEPC;
    const float c1 = -1.2f + (float)((p0 >> 6) & 63) * STEPC;

    // drain-free phase barrier: orders LDS only; vmcnt queue stays in flight
    auto phase_barrier = [&]() {
        __builtin_amdgcn_sched_barrier(0);
        asm volatile("s_waitcnt lgkmcnt(0)" ::: "memory");
        __builtin_amdgcn_s_barrier();
        __builtin_amdgcn_sched_barrier(0);
    };

    // per-lane bases
    const int vWoffB = hi * 32768 + lm * 16;             // W: loop-constant byte voffset
    const _Float16* hb = hbuf2 + hi * 512 + lm * 8;      // A: LDS base, imm offsets

    floatx16 acc[2][2];

    auto zero_acc = [&]() {
#pragma unroll
        for (int mb = 0; mb < 2; ++mb)
#pragma unroll
            for (int nt = 0; nt < 2; ++nt)
#pragma unroll
                for (int r = 0; r < 16; ++r) acc[mb][nt][r] = 0.f;
    };

    // asm-pinned W-fragment load pair: saddr uniform, voffset constant, imm nt
    auto issueW = [&](const _Float16* base, int ks, half8 (&wf)[2]) {
        const _Float16* sp = base + ks * 512;            // uniform (SALU add)
        asm volatile("global_load_dwordx4 %0, %2, %3\n\t"
                     "global_load_dwordx4 %1, %2, %3 offset:512"
                     : "=v"(wf[0]), "=v"(wf[1])
                     : "v"(vWoffB), "s"(sp)
                     : "memory");
    };

    auto loadA = [&](int ks, half8 (&a)[2]) {
        const _Float16* hp = hb + ks * 1024;
        a[0] = *(const half8*)(hp);            // mb=0, pure offset-imm ds_read
        a[1] = *(const half8*)(hp + 256);      // mb=1
    };

    auto compute = [&](half8 (&wf)[2], half8 (&a)[2]) {
        __builtin_amdgcn_s_setprio(1);
#pragma unroll
        for (int nt = 0; nt < 2; ++nt)
#pragma unroll
            for (int mb = 0; mb < 2; ++mb)
                acc[mb][nt] = __builtin_amdgcn_mfma_f32_32x32x16_f16(wf[nt], a[mb], acc[mb][nt], 0, 0, 0);
        __builtin_amdgcn_s_setprio(0);
    };

    const _Float16* wbase0 = wsB + (size_t)uwave * 32768;         // GEMM1 (W1)
    const _Float16* wbase1 = wsB + (size_t)(8 + uwave) * 32768;   // GEMM2 (W2)

    half8 Wq[3][2];        // shared W queue across both GEMMs

    // K-loop body: assumes chunks 0..2 already in flight (issued pre-barrier).
    auto run_gemm_body = [&](const _Float16* base) {
        half8 Aq[2][2];
        loadA(0, Aq[0]);
        loadA(1, Aq[1]);
#pragma unroll
        for (int ks = 0; ks < 32; ++ks) {       // fully unrolled, static indices
            // in flight: pairs for ks .. min(ks+2,31); wait until ks's pair lands
            if (ks <= 29)      asm volatile("s_waitcnt vmcnt(4)" ::: "memory");
            else if (ks == 30) asm volatile("s_waitcnt vmcnt(2)" ::: "memory");
            else               asm volatile("s_waitcnt vmcnt(0)" ::: "memory");
            __builtin_amdgcn_sched_barrier(0);
            compute(Wq[ks % 3], Aq[ks % 2]);
            if (ks + 3 < 32) issueW(base, ks + 3, Wq[ks % 3]);   // slot just consumed
            if (ks + 2 < 32) loadA(ks + 2, Aq[ks % 2]);          // compiler-ordered
        }
    };

    // ---- layer 0, phase A: lw[j] = latw + c0*W0x + c1*W0y; w2c[j] = W0z ----
    {
        const int j = tid;
        const float lwv = latw[b * H + j]
                        + c0 * W0[(H + 0) * H + j]
                        + c1 * W0[(H + 1) * H + j];
        floatx2 v;
        v[0] = lwv;
        v[1] = W0[(H + 2) * H + j];
        *(floatx2*)&lwbuf[2 * j] = v;
    }
    phase_barrier();

    // ---- layer 0, phase B: row m = lane; regions g = wave*8+s ----
    {
        const float c2v = -1.2f + (float)lane * STEPC;
#pragma unroll
        for (int s = 0; s < 8; ++s) {
            const int g = wave * 8 + s;
            const floatx4* lp = (const floatx4*)&lwbuf[g * 16];  // broadcast reads
            half8 hv;
#pragma unroll
            for (int i = 0; i < 4; ++i) {
                const floatx4 pv = lp[i];          // (lw, w2c, lw, w2c)
                hv[2 * i + 0] = (_Float16)silu_f(pv[0] + c2v * pv[1]);
                hv[2 * i + 1] = (_Float16)silu_f(pv[2] + c2v * pv[3]);
            }
            *(half8*)&hbuf2[(g * 64 + lane) * 8] = hv;
        }
    }
    zero_acc();
    // G1 prefetch: issue now (all phase-A/B global loads are consumed by
    // here; sched_barrier in phase_barrier pins ordering). Survives the
    // barrier: no vmcnt drain.
    __builtin_amdgcn_sched_barrier(0);
    issueW(wbase0, 0, Wq[0]);
    issueW(wbase0, 1, Wq[1]);
    issueW(wbase0, 2, Wq[2]);
    phase_barrier();             // h0 ready

    // ---- GEMM 1 ----
    run_gemm_body(wbase0);
    phase_barrier();             // all waves done reading h0

    // writeback h1 = silu(acc + b1): lane owns, per (mb,nt,g), 4 consecutive
    // n = wave*64 + nt*32 + g*8 + hi*4 .. +3 at row m = mb*32+lm -> b64 writes
    {
        _Float16* wb = hbuf2 + (wave * 8) * 512 + lm * 8 + hi * 4;
        floatx4 b1v[2][4];
#pragma unroll
        for (int nt = 0; nt < 2; ++nt)
#pragma unroll
            for (int g = 0; g < 4; ++g)
                b1v[nt][g] = *(const floatx4*)&b1[wave * 64 + nt * 32 + g * 8 + hi * 4];
#pragma unroll
        for (int mb = 0; mb < 2; ++mb)
#pragma unroll
            for (int nt = 0; nt < 2; ++nt)
#pragma unroll
                for (int g = 0; g < 4; ++g) {
                    half4_t hv;
#pragma unroll
                    for (int j = 0; j < 4; ++j)
                        hv[j] = (_Float16)silu_f(acc[mb][nt][g * 4 + j] + b1v[nt][g][j]);
                    *(half4_t*)(wb + (nt * 4 + g) * 512 + mb * 256) = hv;
                }
    }
    zero_acc();
    // G2 prefetch: after b1 loads are consumed (their waits precede this by
    // the sched_barrier), before the h1 barrier -> in flight across it.
    __builtin_amdgcn_sched_barrier(0);
    issueW(wbase1, 0, Wq[0]);
    issueW(wbase1, 1, Wq[1]);
    issueW(wbase1, 2, Wq[2]);
    phase_barrier();             // h1 ready

    // ---- GEMM 2 ----
    run_gemm_body(wbase1);

    // ---- final layer: out = silu(acc + b2) @ W3 + b3, fp32 VALU ----
    {
        floatx4 b2v[2][4], w3v[2][4];
#pragma unroll
        for (int nt = 0; nt < 2; ++nt)
#pragma unroll
            for (int g = 0; g < 4; ++g) {
                const int n0 = wave * 64 + nt * 32 + g * 8 + hi * 4;
                b2v[nt][g] = *(const floatx4*)&b2[n0];
                w3v[nt][g] = *(const floatx4*)&W3[n0];
            }
#pragma unroll
        for (int mb = 0; mb < 2; ++mb) {
            float sum = 0.f;
#pragma unroll
            for (int nt = 0; nt < 2; ++nt)
#pragma unroll
                for (int g = 0; g < 4; ++g)
#pragma unroll
                    for (int j = 0; j < 4; ++j)
                        sum += silu_f(acc[mb][nt][g * 4 + j] + b2v[nt][g][j]) * w3v[nt][g][j];
            sum += __shfl_xor(sum, 32);        // combine hi halves (same m)
            if (hi == 0) partials[wave][mb * 32 + lm] = sum;
        }
    }
    phase_barrier();
    if (tid < MTILE) {
        float o = b3[0];
#pragma unroll
        for (int w = 0; w < 8; ++w) o += partials[w][tid];
        out[(size_t)bi * MTILE + tid] = o;
    }
}

extern "C" void kernel_launch(void* const* d_in, const int* in_sizes, int n_in,
                              void* d_out, int out_size, void* d_ws, size_t ws_size,
                              hipStream_t stream) {
    const float* lat = (const float*)d_in[0];
    const float* W0  = (const float*)d_in[1];
    const float* b0  = (const float*)d_in[2];
    const float* W1  = (const float*)d_in[3];
    const float* b1  = (const float*)d_in[4];
    const float* W2  = (const float*)d_in[5];
    const float* b2  = (const float*)d_in[6];
    const float* W3  = (const float*)d_in[7];
    const float* b3  = (const float*)d_in[8];
    float* out = (float*)d_out;

    float* latw = (float*)d_ws;                               // 4 KB
    _Float16* wsB = (_Float16*)((char*)d_ws + 4096);          // 1 MB

    prep_fused<<<1026, 512, 0, stream>>>(lat, W0, b0, W1, W2, latw, wsB);
    mesh_main<<<NBLK, 512, 0, stream>>>(W0, b1, b2, W3, b3, latw, wsB, out);
}